// Round 1
// baseline (338.380 us; speedup 1.0000x reference)
//
#include <hip/hip_runtime.h>

// EquivariantLayerNorm: per row n (65536 rows), x = in[n] (3x256 fp32),
//   mean-center over D; B = x x^T / D + EPS*diag(2,3,4)   (covar + EPS*I,
//   since reference does 1/sqrt(s+eps) on covar's singular values);
//   out = B^{-1/2} @ x_centered * weight.
// B^{-1/2} via trace-normalized coupled Newton-Schulz (8 iters, fp32).
// One 64-lane wave per row; lane owns 4 contiguous columns (float4).

namespace {

constexpr int kD = 256;
constexpr float kEps = 1e-3f;
constexpr int kNSIters = 8;

// Symmetric 3x3 stored as {a00,a01,a02,a11,a12,a22}. P = M*N (upper triangle;
// M,N commute up to rounding so P is symmetric to fp32 noise).
__device__ __forceinline__ void symmul(const float* M, const float* N, float* P) {
    P[0] = M[0]*N[0] + M[1]*N[1] + M[2]*N[2];
    P[1] = M[0]*N[1] + M[1]*N[3] + M[2]*N[4];
    P[2] = M[0]*N[2] + M[1]*N[4] + M[2]*N[5];
    P[3] = M[1]*N[1] + M[3]*N[3] + M[4]*N[4];
    P[4] = M[1]*N[2] + M[3]*N[4] + M[4]*N[5];
    P[5] = M[2]*N[2] + M[4]*N[4] + M[5]*N[5];
}

__global__ __launch_bounds__(256) void eqln_kernel(const float* __restrict__ in,
                                                   const float* __restrict__ wptr,
                                                   float* __restrict__ out,
                                                   int nrows) {
    const int lane = threadIdx.x & 63;
    const int row  = blockIdx.x * (blockDim.x >> 6) + (threadIdx.x >> 6);
    if (row >= nrows) return;

    const size_t base = (size_t)row * (3 * kD);
    const int col = lane * 4;

    const float4 x0 = *(const float4*)(in + base + 0 * kD + col);
    const float4 x1 = *(const float4*)(in + base + 1 * kD + col);
    const float4 x2 = *(const float4*)(in + base + 2 * kD + col);
    const float4 w  = *(const float4*)(wptr + col);

    // Single-pass raw sums: S_v and Gram Q_uv (9 partials per lane).
    float s[9];
    s[0] = x0.x + x0.y + x0.z + x0.w;
    s[1] = x1.x + x1.y + x1.z + x1.w;
    s[2] = x2.x + x2.y + x2.z + x2.w;
    s[3] = x0.x*x0.x + x0.y*x0.y + x0.z*x0.z + x0.w*x0.w;
    s[4] = x0.x*x1.x + x0.y*x1.y + x0.z*x1.z + x0.w*x1.w;
    s[5] = x0.x*x2.x + x0.y*x2.y + x0.z*x2.z + x0.w*x2.w;
    s[6] = x1.x*x1.x + x1.y*x1.y + x1.z*x1.z + x1.w*x1.w;
    s[7] = x1.x*x2.x + x1.y*x2.y + x1.z*x2.z + x1.w*x2.w;
    s[8] = x2.x*x2.x + x2.y*x2.y + x2.z*x2.z + x2.w*x2.w;

    // Wave-wide butterfly reduction (wave = 64 lanes). Every lane ends with
    // the full sums -- no broadcast needed.
    #pragma unroll
    for (int off = 32; off > 0; off >>= 1) {
        #pragma unroll
        for (int i = 0; i < 9; ++i) s[i] += __shfl_xor(s[i], off, 64);
    }

    const float inv_d = 1.0f / (float)kD;
    const float m0 = s[0] * inv_d, m1 = s[1] * inv_d, m2 = s[2] * inv_d;

    // B = Q/D - m m^T + EPS*diag(2,3,4)
    float B[6];
    B[0] = s[3] * inv_d - m0 * m0 + 2.0f * kEps;
    B[1] = s[4] * inv_d - m0 * m1;
    B[2] = s[5] * inv_d - m0 * m2;
    B[3] = s[6] * inv_d - m1 * m1 + 3.0f * kEps;
    B[4] = s[7] * inv_d - m1 * m2;
    B[5] = s[8] * inv_d - m2 * m2 + 4.0f * kEps;

    // Coupled Newton-Schulz for A^{-1/2}, A = B / tr(B) (eigenvalues in (0,1]).
    const float tr  = B[0] + B[3] + B[5];
    const float itr = 1.0f / tr;
    float Y[6] = {B[0]*itr, B[1]*itr, B[2]*itr, B[3]*itr, B[4]*itr, B[5]*itr};
    float Z[6] = {1.0f, 0.0f, 0.0f, 1.0f, 0.0f, 1.0f};

    #pragma unroll
    for (int it = 0; it < kNSIters; ++it) {
        float W[6], T[6], Yn[6], Zn[6];
        symmul(Z, Y, W);
        T[0] = 1.5f - 0.5f * W[0];
        T[1] = -0.5f * W[1];
        T[2] = -0.5f * W[2];
        T[3] = 1.5f - 0.5f * W[3];
        T[4] = -0.5f * W[4];
        T[5] = 1.5f - 0.5f * W[5];
        symmul(Y, T, Yn);
        symmul(T, Z, Zn);
        #pragma unroll
        for (int i = 0; i < 6; ++i) { Y[i] = Yn[i]; Z[i] = Zn[i]; }
    }

    // B^{-1/2} = Z / sqrt(tr)
    const float sc  = 1.0f / sqrtf(tr);
    const float M00 = Z[0] * sc, M01 = Z[1] * sc, M02 = Z[2] * sc;
    const float M11 = Z[3] * sc, M12 = Z[4] * sc, M22 = Z[5] * sc;

    // out = M @ (x - m) * weight, on this lane's 4 columns.
    const float a0[4] = {x0.x - m0, x0.y - m0, x0.z - m0, x0.w - m0};
    const float a1[4] = {x1.x - m1, x1.y - m1, x1.z - m1, x1.w - m1};
    const float a2[4] = {x2.x - m2, x2.y - m2, x2.z - m2, x2.w - m2};
    const float wv[4] = {w.x, w.y, w.z, w.w};

    float r0[4], r1[4], r2[4];
    #pragma unroll
    for (int i = 0; i < 4; ++i) {
        r0[i] = (M00 * a0[i] + M01 * a1[i] + M02 * a2[i]) * wv[i];
        r1[i] = (M01 * a0[i] + M11 * a1[i] + M12 * a2[i]) * wv[i];
        r2[i] = (M02 * a0[i] + M12 * a1[i] + M22 * a2[i]) * wv[i];
    }

    *(float4*)(out + base + 0 * kD + col) = make_float4(r0[0], r0[1], r0[2], r0[3]);
    *(float4*)(out + base + 1 * kD + col) = make_float4(r1[0], r1[1], r1[2], r1[3]);
    *(float4*)(out + base + 2 * kD + col) = make_float4(r2[0], r2[1], r2[2], r2[3]);
}

}  // namespace

extern "C" void kernel_launch(void* const* d_in, const int* in_sizes, int n_in,
                              void* d_out, int out_size, void* d_ws, size_t ws_size,
                              hipStream_t stream) {
    (void)n_in; (void)d_ws; (void)ws_size; (void)out_size;
    const float* in   = (const float*)d_in[0];
    const float* wght = (const float*)d_in[1];
    float* out = (float*)d_out;

    const int nrows = in_sizes[0] / (3 * kD);      // 65536
    const int rows_per_block = 256 / 64;           // 4 waves -> 4 rows/block
    const int blocks = (nrows + rows_per_block - 1) / rows_per_block;

    eqln_kernel<<<blocks, 256, 0, stream>>>(in, wght, out, nrows);
}

// Round 2
// 332.436 us; speedup vs baseline: 1.0179x; 1.0179x over previous
//
#include <hip/hip_runtime.h>

// EquivariantLayerNorm: per row n (65536 rows), x = in[n] (3x256 fp32),
//   mean-center over D; B = x x^T / D + EPS*diag(2,3,4)   (covar + EPS*I,
//   since reference does 1/sqrt(s+eps) on covar's singular values);
//   out = B^{-1/2} @ x_centered * weight.
// B^{-1/2} via trace-normalized coupled Newton-Schulz (8 iters, fp32).
//
// R2 layout: 16 lanes per row (4 rows per wave). Lane owns 16 columns via the
// interleaved mapping col = lane_in*4 + j*64 (j=0..3), so every load/store
// instruction is 16 consecutive float4s per row-group -> fully coalesced.
// Butterfly reduction is 4 steps (within the 16-lane group); the serial 3x3
// Newton-Schulz is amortized over 4 rows per wave instead of 1.

namespace {

constexpr int kD = 256;
constexpr float kEps = 1e-3f;
constexpr int kNSIters = 8;

// Symmetric 3x3 stored as {a00,a01,a02,a11,a12,a22}. P = M*N upper triangle
// (M,N commute up to rounding, so P is symmetric to fp32 noise).
__device__ __forceinline__ void symmul(const float* M, const float* N, float* P) {
    P[0] = M[0]*N[0] + M[1]*N[1] + M[2]*N[2];
    P[1] = M[0]*N[1] + M[1]*N[3] + M[2]*N[4];
    P[2] = M[0]*N[2] + M[1]*N[4] + M[2]*N[5];
    P[3] = M[1]*N[1] + M[3]*N[3] + M[4]*N[4];
    P[4] = M[1]*N[2] + M[3]*N[4] + M[4]*N[5];
    P[5] = M[2]*N[2] + M[4]*N[4] + M[5]*N[5];
}

__global__ __launch_bounds__(256) void eqln_kernel(const float* __restrict__ in,
                                                   const float* __restrict__ wptr,
                                                   float* __restrict__ out,
                                                   int nrows) {
    const int tid     = threadIdx.x;
    const int lane_in = tid & 15;                        // lane within row-group
    const int row     = blockIdx.x * (blockDim.x >> 4) + (tid >> 4);
    if (row >= nrows) return;

    const size_t base = (size_t)row * (3 * kD);
    const int coff = lane_in * 4;                        // + j*64 per block j

    // Load this lane's 16 columns of all 3 rows (48 floats in registers).
    float4 x[3][4];
    #pragma unroll
    for (int v = 0; v < 3; ++v)
        #pragma unroll
        for (int j = 0; j < 4; ++j)
            x[v][j] = *(const float4*)(in + base + v * kD + j * 64 + coff);

    // Single-pass raw sums: S_v and Gram Q_uv (9 partials per lane).
    float s[9] = {0.f, 0.f, 0.f, 0.f, 0.f, 0.f, 0.f, 0.f, 0.f};
    #pragma unroll
    for (int j = 0; j < 4; ++j) {
        const float* a = (const float*)&x[0][j];
        const float* b = (const float*)&x[1][j];
        const float* c = (const float*)&x[2][j];
        #pragma unroll
        for (int k = 0; k < 4; ++k) {
            s[0] += a[k];      s[1] += b[k];      s[2] += c[k];
            s[3] += a[k]*a[k]; s[4] += a[k]*b[k]; s[5] += a[k]*c[k];
            s[6] += b[k]*b[k]; s[7] += b[k]*c[k]; s[8] += c[k]*c[k];
        }
    }

    // Butterfly over the 16-lane group (xor offsets stay inside the group).
    #pragma unroll
    for (int off = 8; off > 0; off >>= 1) {
        #pragma unroll
        for (int i = 0; i < 9; ++i) s[i] += __shfl_xor(s[i], off, 64);
    }

    const float inv_d = 1.0f / (float)kD;
    const float m0 = s[0] * inv_d, m1 = s[1] * inv_d, m2 = s[2] * inv_d;

    // B = Q/D - m m^T + EPS*diag(2,3,4)
    float B[6];
    B[0] = s[3] * inv_d - m0 * m0 + 2.0f * kEps;
    B[1] = s[4] * inv_d - m0 * m1;
    B[2] = s[5] * inv_d - m0 * m2;
    B[3] = s[6] * inv_d - m1 * m1 + 3.0f * kEps;
    B[4] = s[7] * inv_d - m1 * m2;
    B[5] = s[8] * inv_d - m2 * m2 + 4.0f * kEps;

    // Coupled Newton-Schulz for A^{-1/2}, A = B / tr(B) (eigenvalues in (0,1]).
    const float tr  = B[0] + B[3] + B[5];
    const float itr = 1.0f / tr;
    float Y[6] = {B[0]*itr, B[1]*itr, B[2]*itr, B[3]*itr, B[4]*itr, B[5]*itr};
    float Z[6] = {1.0f, 0.0f, 0.0f, 1.0f, 0.0f, 1.0f};

    #pragma unroll
    for (int it = 0; it < kNSIters; ++it) {
        float W[6], T[6], Yn[6], Zn[6];
        symmul(Z, Y, W);
        T[0] = 1.5f - 0.5f * W[0];
        T[1] = -0.5f * W[1];
        T[2] = -0.5f * W[2];
        T[3] = 1.5f - 0.5f * W[3];
        T[4] = -0.5f * W[4];
        T[5] = 1.5f - 0.5f * W[5];
        symmul(Y, T, Yn);
        symmul(T, Z, Zn);
        #pragma unroll
        for (int i = 0; i < 6; ++i) { Y[i] = Yn[i]; Z[i] = Zn[i]; }
    }

    // B^{-1/2} = Z / sqrt(tr)
    const float sc  = 1.0f / sqrtf(tr);
    const float M00 = Z[0] * sc, M01 = Z[1] * sc, M02 = Z[2] * sc;
    const float M11 = Z[3] * sc, M12 = Z[4] * sc, M22 = Z[5] * sc;

    // out = M @ (x - m) * weight on this lane's 16 columns.
    #pragma unroll
    for (int j = 0; j < 4; ++j) {
        const float4 wv = *(const float4*)(wptr + j * 64 + coff);
        const float* a  = (const float*)&x[0][j];
        const float* b  = (const float*)&x[1][j];
        const float* c  = (const float*)&x[2][j];
        const float* w  = (const float*)&wv;
        float4 r0, r1, r2;
        float* p0 = (float*)&r0; float* p1 = (float*)&r1; float* p2 = (float*)&r2;
        #pragma unroll
        for (int k = 0; k < 4; ++k) {
            const float a0 = a[k] - m0;
            const float a1 = b[k] - m1;
            const float a2 = c[k] - m2;
            p0[k] = (M00 * a0 + M01 * a1 + M02 * a2) * w[k];
            p1[k] = (M01 * a0 + M11 * a1 + M12 * a2) * w[k];
            p2[k] = (M02 * a0 + M12 * a1 + M22 * a2) * w[k];
        }
        *(float4*)(out + base + 0 * kD + j * 64 + coff) = r0;
        *(float4*)(out + base + 1 * kD + j * 64 + coff) = r1;
        *(float4*)(out + base + 2 * kD + j * 64 + coff) = r2;
    }
}

}  // namespace

extern "C" void kernel_launch(void* const* d_in, const int* in_sizes, int n_in,
                              void* d_out, int out_size, void* d_ws, size_t ws_size,
                              hipStream_t stream) {
    (void)n_in; (void)d_ws; (void)ws_size; (void)out_size;
    const float* in   = (const float*)d_in[0];
    const float* wght = (const float*)d_in[1];
    float* out = (float*)d_out;

    const int nrows = in_sizes[0] / (3 * kD);      // 65536
    const int rows_per_block = 256 / 16;           // 16 lanes per row -> 16 rows/block
    const int blocks = (nrows + rows_per_block - 1) / rows_per_block;

    eqln_kernel<<<blocks, 256, 0, stream>>>(in, wght, out, nrows);
}